// Round 1
// baseline (212.110 us; speedup 1.0000x reference)
//
#include <hip/hip_runtime.h>
#include <hip/hip_bf16.h>
#include <math.h>

#define SS 2048
#define HH 16
#define DD 128
#define QBLK 64
#define KVBLK 64

typedef __attribute__((ext_vector_type(8))) short bf16x8;
typedef __attribute__((ext_vector_type(4))) float f32x4;

__device__ __forceinline__ ushort f2bf(float f) {
  __hip_bfloat16 h = __float2bfloat16(f);
  return __builtin_bit_cast(ushort, h);
}

__global__ __launch_bounds__(256, 2)
void attn_fwd(const float* __restrict__ Q, const float* __restrict__ K,
              const float* __restrict__ V, float* __restrict__ O) {
  // LDS: K tile row-major (padded), V tile transposed (padded), per-wave P buffer
  __shared__ alignas(16) ushort Klds[KVBLK][136];   // 17408 B
  __shared__ alignas(16) ushort VTlds[DD][72];      // 18432 B
  __shared__ alignas(16) ushort Plds[4][16][72];    //  9216 B

  const int tid  = threadIdx.x;
  const int lane = tid & 63;
  const int wid  = tid >> 6;
  const int n    = lane & 15;   // MFMA "col" lane index
  const int g    = lane >> 4;   // MFMA k-group / row-group

  const int h  = blockIdx.x & (HH - 1);
  const int qt = (SS / QBLK - 1) - (blockIdx.x >> 4);  // descending: big tiles first
  const int qb = qt * QBLK;
  const int qw = qb + 16 * wid;                        // this wave's first q row

  // fold log2(e) into the softmax scale -> use exp2 everywhere
  const float SCALE = 1.44269504088896f / sqrtf((float)DD);

  // ---- preload Q fragments (A operand), scaled, bf16 ----
  bf16x8 qfrag[4];
  {
    const float* qrow = Q + ((size_t)(qw + n) * HH + h) * DD;
    #pragma unroll
    for (int ks = 0; ks < 4; ++ks) {
      const int d0 = 32 * ks + 8 * g;
      float4 x = *(const float4*)&qrow[d0];
      float4 y = *(const float4*)&qrow[d0 + 4];
      bf16x8 a;
      a[0] = (short)f2bf(x.x * SCALE); a[1] = (short)f2bf(x.y * SCALE);
      a[2] = (short)f2bf(x.z * SCALE); a[3] = (short)f2bf(x.w * SCALE);
      a[4] = (short)f2bf(y.x * SCALE); a[5] = (short)f2bf(y.y * SCALE);
      a[6] = (short)f2bf(y.z * SCALE); a[7] = (short)f2bf(y.w * SCALE);
      qfrag[ks] = a;
    }
  }

  f32x4 acc[8];
  #pragma unroll
  for (int d0 = 0; d0 < 8; ++d0) { acc[d0][0]=0.f; acc[d0][1]=0.f; acc[d0][2]=0.f; acc[d0][3]=0.f; }
  float m[4] = { -INFINITY, -INFINITY, -INFINITY, -INFINITY };
  float l[4] = { 0.f, 0.f, 0.f, 0.f };

  const float* Kbase = K + (size_t)h * DD;
  const float* Vbase = V + (size_t)h * DD;
  const int nt = qb / KVBLK + 1;

  for (int itile = 0; itile < nt; ++itile) {
    const int t0 = itile * KVBLK;
    __syncthreads();   // all waves done reading previous K/V tiles

    // ---- stage K tile: row-major bf16 ----
    #pragma unroll
    for (int it = 0; it < 8; ++it) {
      int li = tid + it * 256;           // float4 index, 0..2047
      int t  = li >> 5;                  // 0..63
      int c4 = (li & 31) << 2;           // 0,4,...,124
      float4 x = *(const float4*)&Kbase[(size_t)(t0 + t) * (HH * DD) + c4];
      ushort4 w;
      w.x = f2bf(x.x); w.y = f2bf(x.y); w.z = f2bf(x.z); w.w = f2bf(x.w);
      *(ushort4*)&Klds[t][c4] = w;
    }

    // ---- stage V tile transposed: VT[d][t] bf16 ----
    {
      const int dd0 = wid * 16 + n;      // 0..63
      const int tq4 = g * 4;
      #pragma unroll
      for (int half = 0; half < 2; ++half) {
        int dd = dd0 + half * 64;
        #pragma unroll
        for (int j = 0; j < 4; ++j) {
          int tt = 16 * j + tq4;
          const float* vp = &Vbase[(size_t)(t0 + tt) * (HH * DD) + dd];
          ushort4 w;
          w.x = f2bf(vp[0]);
          w.y = f2bf(vp[HH * DD]);
          w.z = f2bf(vp[2 * HH * DD]);
          w.w = f2bf(vp[3 * HH * DD]);
          *(ushort4*)&VTlds[dd][tt] = w;
        }
      }
    }
    __syncthreads();

    // ---- QK^T: S[q][t], 16x64 per wave ----
    f32x4 s[4];
    #pragma unroll
    for (int sub = 0; sub < 4; ++sub) { s[sub][0]=0.f; s[sub][1]=0.f; s[sub][2]=0.f; s[sub][3]=0.f; }
    #pragma unroll
    for (int ks = 0; ks < 4; ++ks) {
      #pragma unroll
      for (int sub = 0; sub < 4; ++sub) {
        bf16x8 b = *(const bf16x8*)&Klds[sub * 16 + n][32 * ks + 8 * g];
        s[sub] = __builtin_amdgcn_mfma_f32_16x16x32_bf16(qfrag[ks], b, s[sub], 0, 0, 0);
      }
    }

    // ---- causal mask (diagonal tiles only). lane holds S[qw+4g+r][t0+sub*16+n]
    if (t0 + KVBLK - 1 > qw) {
      #pragma unroll
      for (int sub = 0; sub < 4; ++sub) {
        int tg = t0 + sub * 16 + n;
        #pragma unroll
        for (int r = 0; r < 4; ++r) {
          int qg = qw + 4 * g + r;
          if (tg > qg) s[sub][r] = -INFINITY;
        }
      }
    }

    // ---- online softmax (log2 domain) ----
    float mr[4];
    #pragma unroll
    for (int r = 0; r < 4; ++r)
      mr[r] = fmaxf(fmaxf(s[0][r], s[1][r]), fmaxf(s[2][r], s[3][r]));
    #pragma unroll
    for (int off = 1; off <= 8; off <<= 1) {
      #pragma unroll
      for (int r = 0; r < 4; ++r)
        mr[r] = fmaxf(mr[r], __shfl_xor(mr[r], off));
    }
    float corr[4];
    #pragma unroll
    for (int r = 0; r < 4; ++r) {
      float mn = fmaxf(m[r], mr[r]);
      corr[r] = exp2f(m[r] - mn);
      m[r] = mn;
    }
    float sr[4] = { 0.f, 0.f, 0.f, 0.f };
    #pragma unroll
    for (int sub = 0; sub < 4; ++sub) {
      #pragma unroll
      for (int r = 0; r < 4; ++r) {
        float p = exp2f(s[sub][r] - m[r]);
        sr[r] += p;
        Plds[wid][4 * g + r][sub * 16 + n] = f2bf(p);
      }
    }
    #pragma unroll
    for (int off = 1; off <= 8; off <<= 1) {
      #pragma unroll
      for (int r = 0; r < 4; ++r)
        sr[r] += __shfl_xor(sr[r], off);
    }
    #pragma unroll
    for (int r = 0; r < 4; ++r) l[r] = l[r] * corr[r] + sr[r];
    #pragma unroll
    for (int d0 = 0; d0 < 8; ++d0) {
      #pragma unroll
      for (int r = 0; r < 4; ++r) acc[d0][r] *= corr[r];
    }

    // ---- PV: O += P * V  (A = P from LDS, B = VT from LDS) ----
    #pragma unroll
    for (int ks = 0; ks < 2; ++ks) {
      bf16x8 a = *(const bf16x8*)&Plds[wid][n][32 * ks + 8 * g];
      #pragma unroll
      for (int d0 = 0; d0 < 8; ++d0) {
        bf16x8 b = *(const bf16x8*)&VTlds[d0 * 16 + n][32 * ks + 8 * g];
        acc[d0] = __builtin_amdgcn_mfma_f32_16x16x32_bf16(a, b, acc[d0], 0, 0, 0);
      }
    }
  }

  // ---- epilogue: normalize and store fp32 ----
  float invl[4];
  #pragma unroll
  for (int r = 0; r < 4; ++r) invl[r] = 1.0f / l[r];
  #pragma unroll
  for (int d0 = 0; d0 < 8; ++d0) {
    #pragma unroll
    for (int r = 0; r < 4; ++r) {
      O[((size_t)(qw + 4 * g + r) * HH + h) * DD + d0 * 16 + n] = acc[d0][r] * invl[r];
    }
  }
}

extern "C" void kernel_launch(void* const* d_in, const int* in_sizes, int n_in,
                              void* d_out, int out_size, void* d_ws, size_t ws_size,
                              hipStream_t stream) {
  const float* Q = (const float*)d_in[0];
  const float* K = (const float*)d_in[1];
  const float* V = (const float*)d_in[2];
  float* O = (float*)d_out;
  dim3 grid((SS / QBLK) * HH);   // 512 blocks
  attn_fwd<<<grid, 256, 0, stream>>>(Q, K, V, O);
}

// Round 2
// 75.902 us; speedup vs baseline: 2.7945x; 2.7945x over previous
//
#include <hip/hip_runtime.h>
#include <hip/hip_bf16.h>
#include <math.h>

#define SS 2048
#define HH 16
#define DD 128
#define HD (HH*DD)
#define QBLK 64
#define KVBLK 64

typedef __attribute__((ext_vector_type(8))) short bf16x8;
typedef __attribute__((ext_vector_type(4))) float f32x4;

#if __has_builtin(__builtin_amdgcn_exp2f)
#define EXP2(x) __builtin_amdgcn_exp2f(x)
#else
#define EXP2(x) exp2f(x)
#endif

__device__ __forceinline__ ushort f2bf(float f) {
  __hip_bfloat16 h = __float2bfloat16(f);
  return __builtin_bit_cast(ushort, h);
}

__global__ __launch_bounds__(256, 2)
void attn_fwd(const float* __restrict__ Q, const float* __restrict__ K,
              const float* __restrict__ V, float* __restrict__ O) {
  __shared__ alignas(16) ushort Klds[KVBLK][136];   // 17408 B
  __shared__ alignas(16) ushort VTlds[DD][72];      // 18432 B
  __shared__ alignas(16) ushort Plds[4][16][72];    //  9216 B

  const int tid  = threadIdx.x;
  const int lane = tid & 63;
  const int wid  = tid >> 6;
  const int n    = lane & 15;   // MFMA "col" lane index
  const int g    = lane >> 4;   // MFMA k-group / row-group

  const int h  = blockIdx.x & (HH - 1);
  const int j  = blockIdx.x >> 4;
  // pair blocks (b, b+256): qt sums to 31 -> balanced CU workloads
  const int qt = (j < 16) ? (31 - j) : (j - 16);
  const int qb = qt * QBLK;
  const int qw = qb + 16 * wid;

  const float SCALE = 1.44269504088896f / sqrtf((float)DD);

  // ---- preload Q fragments (A operand), scaled, bf16 ----
  bf16x8 qfrag[4];
  {
    const float* qrow = Q + ((size_t)(qw + n) * HH + h) * DD;
    #pragma unroll
    for (int ks = 0; ks < 4; ++ks) {
      const int d0 = 32 * ks + 8 * g;
      float4 x = *(const float4*)&qrow[d0];
      float4 y = *(const float4*)&qrow[d0 + 4];
      bf16x8 a;
      a[0] = (short)f2bf(x.x * SCALE); a[1] = (short)f2bf(x.y * SCALE);
      a[2] = (short)f2bf(x.z * SCALE); a[3] = (short)f2bf(x.w * SCALE);
      a[4] = (short)f2bf(y.x * SCALE); a[5] = (short)f2bf(y.y * SCALE);
      a[6] = (short)f2bf(y.z * SCALE); a[7] = (short)f2bf(y.w * SCALE);
      qfrag[ks] = a;
    }
  }

  f32x4 acc[8];
  #pragma unroll
  for (int d0 = 0; d0 < 8; ++d0) { acc[d0][0]=0.f; acc[d0][1]=0.f; acc[d0][2]=0.f; acc[d0][3]=0.f; }
  float m[4] = { -INFINITY, -INFINITY, -INFINITY, -INFINITY };
  float l[4] = { 0.f, 0.f, 0.f, 0.f };

  const float* Kbase = K + (size_t)h * DD;
  const float* Vbase = V + (size_t)h * DD;
  const int nt = qb / KVBLK + 1;

  // ---- prefetch registers (tile i+1 in flight while computing tile i) ----
  float4 kreg[8];
  float4 vreg[8];

  // prefetch tile 0
  {
    #pragma unroll
    for (int it = 0; it < 8; ++it) {
      int li = tid + it * 256;
      int t  = li >> 5;
      int c4 = (li & 31) << 2;
      kreg[it] = *(const float4*)&Kbase[(size_t)t * HD + c4];
    }
    const int dd0 = wid * 16 + n;
    #pragma unroll
    for (int half = 0; half < 2; ++half) {
      #pragma unroll
      for (int jj = 0; jj < 4; ++jj) {
        const float* vp = &Vbase[(size_t)(16 * jj + 4 * g) * HD + (dd0 + 64 * half)];
        vreg[half * 4 + jj] = make_float4(vp[0], vp[HD], vp[2 * HD], vp[3 * HD]);
      }
    }
  }

  for (int itile = 0; itile < nt; ++itile) {
    __syncthreads();   // all waves done reading LDS from previous tile

    // ---- write prefetched regs -> LDS (bf16) ----
    #pragma unroll
    for (int it = 0; it < 8; ++it) {
      int li = tid + it * 256;
      int t  = li >> 5;
      int c4 = (li & 31) << 2;
      float4 x = kreg[it];
      ushort4 w;
      w.x = f2bf(x.x); w.y = f2bf(x.y); w.z = f2bf(x.z); w.w = f2bf(x.w);
      *(ushort4*)&Klds[t][c4] = w;
    }
    {
      const int dd0 = wid * 16 + n;
      #pragma unroll
      for (int half = 0; half < 2; ++half) {
        #pragma unroll
        for (int jj = 0; jj < 4; ++jj) {
          float4 x = vreg[half * 4 + jj];
          ushort4 w;
          w.x = f2bf(x.x); w.y = f2bf(x.y); w.z = f2bf(x.z); w.w = f2bf(x.w);
          *(ushort4*)&VTlds[dd0 + 64 * half][16 * jj + 4 * g] = w;
        }
      }
    }
    __syncthreads();   // LDS tile ready

    // ---- issue prefetch for tile i+1 (in flight during compute) ----
    if (itile + 1 < nt) {
      const int t0n = (itile + 1) * KVBLK;
      #pragma unroll
      for (int it = 0; it < 8; ++it) {
        int li = tid + it * 256;
        int t  = li >> 5;
        int c4 = (li & 31) << 2;
        kreg[it] = *(const float4*)&Kbase[(size_t)(t0n + t) * HD + c4];
      }
      const int dd0 = wid * 16 + n;
      #pragma unroll
      for (int half = 0; half < 2; ++half) {
        #pragma unroll
        for (int jj = 0; jj < 4; ++jj) {
          const float* vp = &Vbase[(size_t)(t0n + 16 * jj + 4 * g) * HD + (dd0 + 64 * half)];
          vreg[half * 4 + jj] = make_float4(vp[0], vp[HD], vp[2 * HD], vp[3 * HD]);
        }
      }
    }

    const int t0 = itile * KVBLK;

    // ---- QK^T: S[q][t], 16x64 per wave ----
    f32x4 s[4];
    #pragma unroll
    for (int sub = 0; sub < 4; ++sub) { s[sub][0]=0.f; s[sub][1]=0.f; s[sub][2]=0.f; s[sub][3]=0.f; }
    #pragma unroll
    for (int ks = 0; ks < 4; ++ks) {
      #pragma unroll
      for (int sub = 0; sub < 4; ++sub) {
        bf16x8 b = *(const bf16x8*)&Klds[sub * 16 + n][32 * ks + 8 * g];
        s[sub] = __builtin_amdgcn_mfma_f32_16x16x32_bf16(qfrag[ks], b, s[sub], 0, 0, 0);
      }
    }

    // ---- causal mask (diagonal tiles only). lane holds S[qw+4g+r][t0+sub*16+n]
    if (t0 + KVBLK - 1 > qw) {
      #pragma unroll
      for (int sub = 0; sub < 4; ++sub) {
        int tg = t0 + sub * 16 + n;
        #pragma unroll
        for (int r = 0; r < 4; ++r) {
          int qg = qw + 4 * g + r;
          if (tg > qg) s[sub][r] = -INFINITY;
        }
      }
    }

    // ---- online softmax (log2 domain) ----
    float mr[4];
    #pragma unroll
    for (int r = 0; r < 4; ++r)
      mr[r] = fmaxf(fmaxf(s[0][r], s[1][r]), fmaxf(s[2][r], s[3][r]));
    #pragma unroll
    for (int off = 1; off <= 8; off <<= 1) {
      #pragma unroll
      for (int r = 0; r < 4; ++r)
        mr[r] = fmaxf(mr[r], __shfl_xor(mr[r], off));
    }
    float corr[4];
    #pragma unroll
    for (int r = 0; r < 4; ++r) {
      float mn = fmaxf(m[r], mr[r]);
      corr[r] = EXP2(m[r] - mn);
      m[r] = mn;
    }
    float sr[4] = { 0.f, 0.f, 0.f, 0.f };
    #pragma unroll
    for (int sub = 0; sub < 4; ++sub) {
      #pragma unroll
      for (int r = 0; r < 4; ++r) {
        float p = EXP2(s[sub][r] - m[r]);
        sr[r] += p;
        Plds[wid][4 * g + r][sub * 16 + n] = f2bf(p);
      }
    }
    #pragma unroll
    for (int off = 1; off <= 8; off <<= 1) {
      #pragma unroll
      for (int r = 0; r < 4; ++r)
        sr[r] += __shfl_xor(sr[r], off);
    }
    #pragma unroll
    for (int r = 0; r < 4; ++r) l[r] = l[r] * corr[r] + sr[r];
    #pragma unroll
    for (int d0 = 0; d0 < 8; ++d0) {
      #pragma unroll
      for (int r = 0; r < 4; ++r) acc[d0][r] *= corr[r];
    }

    // ---- PV: O += P * V  (A = P from LDS, B = VT from LDS) ----
    #pragma unroll
    for (int ks = 0; ks < 2; ++ks) {
      bf16x8 a = *(const bf16x8*)&Plds[wid][n][32 * ks + 8 * g];
      #pragma unroll
      for (int d0 = 0; d0 < 8; ++d0) {
        bf16x8 b = *(const bf16x8*)&VTlds[d0 * 16 + n][32 * ks + 8 * g];
        acc[d0] = __builtin_amdgcn_mfma_f32_16x16x32_bf16(a, b, acc[d0], 0, 0, 0);
      }
    }
  }

  // ---- epilogue: normalize and store fp32 ----
  float invl[4];
  #pragma unroll
  for (int r = 0; r < 4; ++r) invl[r] = 1.0f / l[r];
  #pragma unroll
  for (int d0 = 0; d0 < 8; ++d0) {
    #pragma unroll
    for (int r = 0; r < 4; ++r) {
      O[((size_t)(qw + 4 * g + r) * HH + h) * DD + d0 * 16 + n] = acc[d0][r] * invl[r];
    }
  }
}

extern "C" void kernel_launch(void* const* d_in, const int* in_sizes, int n_in,
                              void* d_out, int out_size, void* d_ws, size_t ws_size,
                              hipStream_t stream) {
  const float* Q = (const float*)d_in[0];
  const float* K = (const float*)d_in[1];
  const float* V = (const float*)d_in[2];
  float* O = (float*)d_out;
  dim3 grid((SS / QBLK) * HH);   // 512 blocks
  attn_fwd<<<grid, 256, 0, stream>>>(Q, K, V, O);
}